// Round 4
// baseline (49.023 us; speedup 1.0000x reference)
//
#include <hip/hip_runtime.h>
#include <math.h>

// KDE via bf16 hi/lo split MFMA, prescaled so the inner loop is exp2(C)+add.
//   arg = k2l*(dot(e,b) - 0.5|e|^2 - 0.5|b|^2),  k2l = exp(-2 log_bw)*log2(e)
//   eval data prescaled by k2l; norm constants prescaled and 3-way bf16 split
//   (slots 0-2 base / 3-5 eval of the norms MFMA). Per 32x32 tile:
//     C = Ah*Bh + Ah*Bl + Al*Bh + An*Bn ; out += exp2(C)
// Base planes interleaved per tile (Ah|Al|An @ +0/+1024/+2048 B) -> one vaddr,
// 3 imm-offset loads, one pointer increment per tile. unroll 1 keeps VGPR<=64.

#define LOG_2PI_F 1.8378770664093453f
#define LOG2E_F   1.4426950408889634f

#define M_PTS 8192
#define N_PTS 16384
#define NCH   64                       // N chunks
#define ROWS_PER_CHUNK (N_PTS / NCH)   // 256
#define TPC (ROWS_PER_CHUNK / 32)      // 8 tiles per chunk
#define TILE_USH 1536                  // 3 planes x 32 rows x 16 bf16
#define CHUNK_USH (TPC * TILE_USH)

typedef __attribute__((ext_vector_type(8)))  short bf16x8;
typedef __attribute__((ext_vector_type(16))) float f32x16;

static __device__ __forceinline__ unsigned short f2bf(float x) {
    unsigned u = __float_as_uint(x);
    u += 0x7fffu + ((u >> 16) & 1u);          // RNE
    return (unsigned short)(u >> 16);
}
static __device__ __forceinline__ float bf2f(unsigned short h) {
    return __uint_as_float(((unsigned)h) << 16);
}
static __device__ __forceinline__ uint4 pack8(const unsigned short* a) {
    uint4 u;
    u.x = (unsigned)a[0] | ((unsigned)a[1] << 16);
    u.y = (unsigned)a[2] | ((unsigned)a[3] << 16);
    u.z = (unsigned)a[4] | ((unsigned)a[5] << 16);
    u.w = (unsigned)a[6] | ((unsigned)a[7] << 16);
    return u;
}

// ---------------------------------------------------------------------------
// pack both inputs. base rows -> tile-interleaved layout; eval rows -> planar.
__global__ __launch_bounds__(256) void kde_pack(
        const float* __restrict__ xe, const float* __restrict__ xb,
        const float* __restrict__ log_bw,
        unsigned short* __restrict__ bint,
        unsigned short* __restrict__ eh, unsigned short* __restrict__ el,
        unsigned short* __restrict__ en) {
    int r = blockIdx.x * 256 + threadIdx.x;
    if (r >= N_PTS + M_PTS) return;
    const float k2l = __expf(-2.f * log_bw[0]) * LOG2E_F;

    int is_eval = (r >= N_PTS);
    int rr = is_eval ? (r - N_PTS) : r;
    const float* src = is_eval ? xe : xb;
    float dscale = is_eval ? k2l : 1.0f;       // eval data prescaled

    const float4* row = (const float4*)(src + (size_t)rr * 16);
    unsigned short hs[16], ls[16], ns[16];
    float s = 0.f;
#pragma unroll
    for (int k = 0; k < 4; ++k) {
        float4 v = row[k];
        float c[4] = {v.x, v.y, v.z, v.w};
#pragma unroll
        for (int j = 0; j < 4; ++j) {
            s = fmaf(c[j], c[j], s);
            float d = c[j] * dscale;
            unsigned short h = f2bf(d);
            hs[k*4+j] = h;
            ls[k*4+j] = f2bf(d - bf2f(h));
        }
    }
    // 3-way bf16 split of the scaled norm constant: residual ~2^-27 rel
    float cn = -0.5f * s * k2l;
    unsigned short c0 = f2bf(cn);
    float r1 = cn - bf2f(c0);
    unsigned short c1 = f2bf(r1);
    unsigned short c2 = f2bf(r1 - bf2f(c1));
#pragma unroll
    for (int i = 0; i < 16; ++i) ns[i] = 0;
    if (is_eval) {
        ns[0] = 0x3F80; ns[1] = 0x3F80; ns[2] = 0x3F80;
        ns[3] = c0;     ns[4] = c1;     ns[5] = c2;
    } else {
        ns[0] = c0;     ns[1] = c1;     ns[2] = c2;
        ns[3] = 0x3F80; ns[4] = 0x3F80; ns[5] = 0x3F80;
    }

    if (is_eval) {
        uint4* dh = (uint4*)(eh + (size_t)rr * 16);
        uint4* dl = (uint4*)(el + (size_t)rr * 16);
        uint4* dn = (uint4*)(en + (size_t)rr * 16);
        dh[0] = pack8(hs); dh[1] = pack8(hs + 8);
        dl[0] = pack8(ls); dl[1] = pack8(ls + 8);
        dn[0] = pack8(ns); dn[1] = pack8(ns + 8);
    } else {
        int t = rr >> 5, q = rr & 31;
        unsigned short* base = bint + (size_t)t * TILE_USH + q * 16;
        uint4* dh = (uint4*)(base);
        uint4* dl = (uint4*)(base + 512);
        uint4* dn = (uint4*)(base + 1024);
        dh[0] = pack8(hs); dh[1] = pack8(hs + 8);
        dl[0] = pack8(ls); dl[1] = pack8(ls + 8);
        dn[0] = pack8(ns); dn[1] = pack8(ns + 8);
    }
}

// ---------------------------------------------------------------------------
// main: wave owns ONE 32x32 C tile (32 eval rows) x one base chunk (256 rows).
// 4 waves/block share the chunk -> L1 reuse. VGPR target <=64 (8 waves/SIMD).
__global__ __launch_bounds__(256, 8) void kde_mfma(
        const unsigned short* __restrict__ eh, const unsigned short* __restrict__ el,
        const unsigned short* __restrict__ en,
        const unsigned short* __restrict__ bint,
        float* __restrict__ part) {
    const int lane = threadIdx.x & 63;
    const int widx = threadIdx.x >> 6;
    const int b = blockIdx.x;                 // 0..4095
    const int chunk = b >> 6;                 // 0..63 (block-uniform)
    const int etp = (b & 63) * 4 + widx;      // 0..255
    const int col = lane & 31;
    const int kg  = lane >> 5;

    // eval (B) fragments — resident for whole kernel
    const size_t eoff = ((size_t)etp * 32 + col) * 16 + (size_t)kg * 8;
    const bf16x8 Bh = *(const bf16x8*)(eh + eoff);
    const bf16x8 Bl = *(const bf16x8*)(el + eoff);
    const bf16x8 Bn = *(const bf16x8*)(en + eoff);

    // base (A): one vaddr, planes at +0 / +512 / +1024 ushorts (imm offsets)
    const unsigned short* pa =
        bint + (size_t)chunk * CHUNK_USH + (size_t)col * 16 + (size_t)kg * 8;

    float acc0 = 0.f, acc1 = 0.f;

#pragma unroll 1
    for (int t = 0; t < TPC; ++t) {
        const bf16x8 Ah = *(const bf16x8*)(pa);
        const bf16x8 Al = *(const bf16x8*)(pa + 512);
        const bf16x8 An = *(const bf16x8*)(pa + 1024);
        pa += TILE_USH;

        f32x16 C;
#pragma unroll
        for (int r = 0; r < 16; ++r) C[r] = 0.f;
        C = __builtin_amdgcn_mfma_f32_32x32x16_bf16(Ah, Bh, C, 0, 0, 0);
        C = __builtin_amdgcn_mfma_f32_32x32x16_bf16(Ah, Bl, C, 0, 0, 0);
        C = __builtin_amdgcn_mfma_f32_32x32x16_bf16(Al, Bh, C, 0, 0, 0);
        C = __builtin_amdgcn_mfma_f32_32x32x16_bf16(An, Bn, C, 0, 0, 0);

#pragma unroll
        for (int r = 0; r < 16; r += 2) {
            acc0 += __builtin_amdgcn_exp2f(C[r]);
            acc1 += __builtin_amdgcn_exp2f(C[r + 1]);
        }
    }

    float s = acc0 + acc1;
    s += __shfl_xor(s, 32, 64);               // fold the two kg row-groups
    if (lane < 32)
        part[(size_t)chunk * M_PTS + (size_t)etp * 32 + col] = s;
}

// ---------------------------------------------------------------------------
__global__ __launch_bounds__(256) void kde_reduce(
        const float* __restrict__ part, const float* __restrict__ log_bw,
        float* __restrict__ out) {
    int m = blockIdx.x * 256 + threadIdx.x;
    if (m >= M_PTS) return;
    float lb = log_bw[0];
    float scale = __expf(-8.f * LOG_2PI_F - lb) / (float)N_PTS;
    float s = 0.f;
#pragma unroll
    for (int c = 0; c < NCH; ++c) s += part[(size_t)c * M_PTS + m];
    out[m] = scale * s;
}

// ---------------------------------------------------------------------------
extern "C" void kernel_launch(void* const* d_in, const int* in_sizes, int n_in,
                              void* d_out, int out_size, void* d_ws, size_t ws_size,
                              hipStream_t stream) {
    const float* xe = (const float*)d_in[0];   // [8192,16]
    const float* xb = (const float*)d_in[1];   // [16384,16]
    const float* lb = (const float*)d_in[2];   // [1]
    float* out = (float*)d_out;                // [8192]

    unsigned short* bint = (unsigned short*)d_ws;                  // 512 tiles * 1536
    unsigned short* eh = bint + (size_t)(N_PTS / 32) * TILE_USH;
    unsigned short* el = eh + (size_t)M_PTS * 16;
    unsigned short* en = el + (size_t)M_PTS * 16;
    float* part = (float*)(en + (size_t)M_PTS * 16);               // NCH*M_PTS floats

    kde_pack<<<(N_PTS + M_PTS) / 256, 256, 0, stream>>>(xe, xb, lb,
                                                        bint, eh, el, en);
    kde_mfma<<<4096, 256, 0, stream>>>(eh, el, en, bint, part);
    kde_reduce<<<M_PTS / 256, 256, 0, stream>>>(part, lb, out);
}

// Round 5
// 48.882 us; speedup vs baseline: 1.0029x; 1.0029x over previous
//
#include <hip/hip_runtime.h>
#include <math.h>

// KDE via bf16 hi/lo split MFMA, prescaled so the inner loop is exp2(C)+add.
//   arg = k2l*(dot(e,b) - 0.5|e|^2 - 0.5|b|^2),  k2l = exp(-2 log_bw)*log2(e)
//   eval data prescaled by k2l; norm constants prescaled and 3-way bf16 split
//   (slots 0-2 base / 3-5 eval of the norms MFMA). Per 32x32 tile:
//     C = Ah*Bh + Ah*Bl + Al*Bh + An*Bn ; out += exp2(C)
// Base planes interleaved per tile (Ah|Al|An @ +0/+1024/+2048 B) -> one vaddr,
// 3 imm-offset loads, one pointer increment per tile. unroll 1 keeps VGPR<=64.

#define LOG_2PI_F 1.8378770664093453f
#define LOG2E_F   1.4426950408889634f

#define M_PTS 8192
#define N_PTS 16384
#define NCH   64                       // N chunks
#define ROWS_PER_CHUNK (N_PTS / NCH)   // 256
#define TPC (ROWS_PER_CHUNK / 32)      // 8 tiles per chunk
#define TILE_USH 1536                  // 3 planes x 32 rows x 16 bf16
#define CHUNK_USH (TPC * TILE_USH)

typedef __attribute__((ext_vector_type(8)))  short bf16x8;
typedef __attribute__((ext_vector_type(16))) float f32x16;

static __device__ __forceinline__ unsigned short f2bf(float x) {
    unsigned u = __float_as_uint(x);
    u += 0x7fffu + ((u >> 16) & 1u);          // RNE
    return (unsigned short)(u >> 16);
}
static __device__ __forceinline__ float bf2f(unsigned short h) {
    return __uint_as_float(((unsigned)h) << 16);
}
static __device__ __forceinline__ uint4 pack8(const unsigned short* a) {
    uint4 u;
    u.x = (unsigned)a[0] | ((unsigned)a[1] << 16);
    u.y = (unsigned)a[2] | ((unsigned)a[3] << 16);
    u.z = (unsigned)a[4] | ((unsigned)a[5] << 16);
    u.w = (unsigned)a[6] | ((unsigned)a[7] << 16);
    return u;
}

// ---------------------------------------------------------------------------
// pack both inputs. base rows -> tile-interleaved layout; eval rows -> planar.
__global__ __launch_bounds__(256) void kde_pack(
        const float* __restrict__ xe, const float* __restrict__ xb,
        const float* __restrict__ log_bw,
        unsigned short* __restrict__ bint,
        unsigned short* __restrict__ eh, unsigned short* __restrict__ el,
        unsigned short* __restrict__ en) {
    int r = blockIdx.x * 256 + threadIdx.x;
    if (r >= N_PTS + M_PTS) return;
    const float k2l = __expf(-2.f * log_bw[0]) * LOG2E_F;

    int is_eval = (r >= N_PTS);
    int rr = is_eval ? (r - N_PTS) : r;
    const float* src = is_eval ? xe : xb;
    float dscale = is_eval ? k2l : 1.0f;       // eval data prescaled

    const float4* row = (const float4*)(src + (size_t)rr * 16);
    unsigned short hs[16], ls[16], ns[16];
    float s = 0.f;
#pragma unroll
    for (int k = 0; k < 4; ++k) {
        float4 v = row[k];
        float c[4] = {v.x, v.y, v.z, v.w};
#pragma unroll
        for (int j = 0; j < 4; ++j) {
            s = fmaf(c[j], c[j], s);
            float d = c[j] * dscale;
            unsigned short h = f2bf(d);
            hs[k*4+j] = h;
            ls[k*4+j] = f2bf(d - bf2f(h));
        }
    }
    // 3-way bf16 split of the scaled norm constant: residual ~2^-27 rel
    float cn = -0.5f * s * k2l;
    unsigned short c0 = f2bf(cn);
    float r1 = cn - bf2f(c0);
    unsigned short c1 = f2bf(r1);
    unsigned short c2 = f2bf(r1 - bf2f(c1));
#pragma unroll
    for (int i = 0; i < 16; ++i) ns[i] = 0;
    if (is_eval) {
        ns[0] = 0x3F80; ns[1] = 0x3F80; ns[2] = 0x3F80;
        ns[3] = c0;     ns[4] = c1;     ns[5] = c2;
    } else {
        ns[0] = c0;     ns[1] = c1;     ns[2] = c2;
        ns[3] = 0x3F80; ns[4] = 0x3F80; ns[5] = 0x3F80;
    }

    if (is_eval) {
        uint4* dh = (uint4*)(eh + (size_t)rr * 16);
        uint4* dl = (uint4*)(el + (size_t)rr * 16);
        uint4* dn = (uint4*)(en + (size_t)rr * 16);
        dh[0] = pack8(hs); dh[1] = pack8(hs + 8);
        dl[0] = pack8(ls); dl[1] = pack8(ls + 8);
        dn[0] = pack8(ns); dn[1] = pack8(ns + 8);
    } else {
        int t = rr >> 5, q = rr & 31;
        unsigned short* base = bint + (size_t)t * TILE_USH + q * 16;
        uint4* dh = (uint4*)(base);
        uint4* dl = (uint4*)(base + 512);
        uint4* dn = (uint4*)(base + 1024);
        dh[0] = pack8(hs); dh[1] = pack8(hs + 8);
        dl[0] = pack8(ls); dl[1] = pack8(ls + 8);
        dn[0] = pack8(ns); dn[1] = pack8(ns + 8);
    }
}

// ---------------------------------------------------------------------------
// main: wave owns ONE 32x32 C tile (32 eval rows) x one base chunk (256 rows).
// 4 waves/block share the chunk -> L1 reuse. VGPR target <=64 (8 waves/SIMD).
__global__ __launch_bounds__(256, 8) void kde_mfma(
        const unsigned short* __restrict__ eh, const unsigned short* __restrict__ el,
        const unsigned short* __restrict__ en,
        const unsigned short* __restrict__ bint,
        float* __restrict__ part) {
    const int lane = threadIdx.x & 63;
    const int widx = threadIdx.x >> 6;
    const int b = blockIdx.x;                 // 0..4095
    const int chunk = b >> 6;                 // 0..63 (block-uniform)
    const int etp = (b & 63) * 4 + widx;      // 0..255
    const int col = lane & 31;
    const int kg  = lane >> 5;

    // eval (B) fragments — resident for whole kernel
    const size_t eoff = ((size_t)etp * 32 + col) * 16 + (size_t)kg * 8;
    const bf16x8 Bh = *(const bf16x8*)(eh + eoff);
    const bf16x8 Bl = *(const bf16x8*)(el + eoff);
    const bf16x8 Bn = *(const bf16x8*)(en + eoff);

    // base (A): one vaddr, planes at +0 / +512 / +1024 ushorts (imm offsets)
    const unsigned short* pa =
        bint + (size_t)chunk * CHUNK_USH + (size_t)col * 16 + (size_t)kg * 8;

    float acc0 = 0.f, acc1 = 0.f;

#pragma unroll 1
    for (int t = 0; t < TPC; ++t) {
        const bf16x8 Ah = *(const bf16x8*)(pa);
        const bf16x8 Al = *(const bf16x8*)(pa + 512);
        const bf16x8 An = *(const bf16x8*)(pa + 1024);
        pa += TILE_USH;

        f32x16 C;
#pragma unroll
        for (int r = 0; r < 16; ++r) C[r] = 0.f;
        C = __builtin_amdgcn_mfma_f32_32x32x16_bf16(Ah, Bh, C, 0, 0, 0);
        C = __builtin_amdgcn_mfma_f32_32x32x16_bf16(Ah, Bl, C, 0, 0, 0);
        C = __builtin_amdgcn_mfma_f32_32x32x16_bf16(Al, Bh, C, 0, 0, 0);
        C = __builtin_amdgcn_mfma_f32_32x32x16_bf16(An, Bn, C, 0, 0, 0);

#pragma unroll
        for (int r = 0; r < 16; r += 2) {
            acc0 += __builtin_amdgcn_exp2f(C[r]);
            acc1 += __builtin_amdgcn_exp2f(C[r + 1]);
        }
    }

    float s = acc0 + acc1;
    s += __shfl_xor(s, 32, 64);               // fold the two kg row-groups
    if (lane < 32)
        part[(size_t)chunk * M_PTS + (size_t)etp * 32 + col] = s;
}

// ---------------------------------------------------------------------------
__global__ __launch_bounds__(256) void kde_reduce(
        const float* __restrict__ part, const float* __restrict__ log_bw,
        float* __restrict__ out) {
    int m = blockIdx.x * 256 + threadIdx.x;
    if (m >= M_PTS) return;
    float lb = log_bw[0];
    float scale = __expf(-8.f * LOG_2PI_F - lb) / (float)N_PTS;
    float s = 0.f;
#pragma unroll
    for (int c = 0; c < NCH; ++c) s += part[(size_t)c * M_PTS + m];
    out[m] = scale * s;
}

// ---------------------------------------------------------------------------
extern "C" void kernel_launch(void* const* d_in, const int* in_sizes, int n_in,
                              void* d_out, int out_size, void* d_ws, size_t ws_size,
                              hipStream_t stream) {
    const float* xe = (const float*)d_in[0];   // [8192,16]
    const float* xb = (const float*)d_in[1];   // [16384,16]
    const float* lb = (const float*)d_in[2];   // [1]
    float* out = (float*)d_out;                // [8192]

    unsigned short* bint = (unsigned short*)d_ws;                  // 512 tiles * 1536
    unsigned short* eh = bint + (size_t)(N_PTS / 32) * TILE_USH;
    unsigned short* el = eh + (size_t)M_PTS * 16;
    unsigned short* en = el + (size_t)M_PTS * 16;
    float* part = (float*)(en + (size_t)M_PTS * 16);               // NCH*M_PTS floats

    kde_pack<<<(N_PTS + M_PTS) / 256, 256, 0, stream>>>(xe, xb, lb,
                                                        bint, eh, el, en);
    kde_mfma<<<4096, 256, 0, stream>>>(eh, el, en, bint, part);
    kde_reduce<<<M_PTS / 256, 256, 0, stream>>>(part, lb, out);
}